// Round 2
// baseline (163.389 us; speedup 1.0000x reference)
//
#include <hip/hip_runtime.h>
#include <hip/hip_fp16.h>

#define PP 9216   // 96*96 pixels per batch

typedef _Float16 f16x8 __attribute__((ext_vector_type(8)));
typedef _Float16 f16x4 __attribute__((ext_vector_type(4)));
typedef float    f32x4 __attribute__((ext_vector_type(4)));

// LDS row strides (in elements). All chosen so row stride in bytes is a
// multiple of 16 (b128-aligned) with decent bank spread.
#define SXW 136   // sX / sK / sQ / sAo (halfs): 272B rows
#define SVW 168   // sVT / sP (halfs): 336B rows
#define SSW 145   // sS (floats): 580B rows, odd dword stride -> conflict-free

// byte offsets into the shared block
#define OFF_A   0                        // sX(39168) / sS(37120) / sP(21504)
#define OFF_K   39168
#define OFF_VT  78336                    // 128*168*2 = 43008
#define OFF_Q   121344                   // 64*136*2 = 17408
#define OFF_AO  138752                   // 17408
#define LDS_BYTES 156160

__device__ __forceinline__ f16x8 cvt8(float4 u0, float4 u1) {
    f16x8 r;
    r[0] = (_Float16)u0.x; r[1] = (_Float16)u0.y;
    r[2] = (_Float16)u0.z; r[3] = (_Float16)u0.w;
    r[4] = (_Float16)u1.x; r[5] = (_Float16)u1.y;
    r[6] = (_Float16)u1.z; r[7] = (_Float16)u1.w;
    return r;
}

// ---------------------------------------------------------------------------
// Fully fused window self-attention. One block per (8x8 tile, batch).
// 256 threads = 4 waves. Phases:
//  P1 stage x halo (12x12 x 128ch) f32->f16 into sX
//  P2 K,V GEMM (144x256x128), V written transposed (sVT[d][pos])
//  P3 Q GEMM (64x128x128)
//  per head: QK^T dense (64x144) -> softmax (reg) -> P f16 -> PV -> sAo
//  P5 proj GEMM (128c x 64px x 128o) -> global out
// ---------------------------------------------------------------------------
__global__ __launch_bounds__(256) void fused_attn(
    const float* __restrict__ x,  const float* __restrict__ wq,
    const float* __restrict__ wk, const float* __restrict__ wv,
    const float* __restrict__ wp, float* __restrict__ out)
{
    __shared__ __align__(16) char smem[LDS_BYTES];
    __shared__ float sInv[64];
    _Float16* sX  = (_Float16*)(smem + OFF_A);
    float*    sS  = (float*)   (smem + OFF_A);   // overlays sX (dead after P3)
    _Float16* sP  = (_Float16*)(smem + OFF_A);   // overlays sS (barrier-fenced)
    _Float16* sK  = (_Float16*)(smem + OFF_K);
    _Float16* sVT = (_Float16*)(smem + OFF_VT);
    _Float16* sQ  = (_Float16*)(smem + OFF_Q);
    _Float16* sAo = (_Float16*)(smem + OFF_AO);

    const int t = threadIdx.x;
    const int w = t >> 6, lane = t & 63, lm = lane & 15, quad = lane >> 4;
    const int x0 = blockIdx.x * 8, y0 = blockIdx.y * 8, b = blockIdx.z;
    const float* xb = x + (size_t)b * 128 * PP;
    float* ob = out + (size_t)b * 128 * PP;

    // ---- P1: stage x halo (f32 -> f16); zero sVT pad columns (K-step pad)
    #pragma unroll 4
    for (int i = 0; i < 72; i++) {
        int e = i * 256 + t;
        int c = e / 144, pos = e - c * 144;
        int hy = pos / 12, hx = pos - hy * 12;
        int gy = y0 - 2 + hy, gx = x0 - 2 + hx;
        float v = 0.f;
        if ((unsigned)gy < 96u && (unsigned)gx < 96u)
            v = xb[(size_t)c * PP + gy * 96 + gx];
        sX[pos * SXW + c] = (_Float16)v;
    }
    if (t < 128) {
        f16x4 z4 = {(_Float16)0, (_Float16)0, (_Float16)0, (_Float16)0};
        #pragma unroll
        for (int j = 0; j < 24; j += 4)
            *(f16x4*)(sVT + t * SVW + 144 + j) = z4;
    }

    // hoist K/V weight fragments (global f32, no LDS dep) over the barrier
    f16x8 BKV[4][4];   // ni: {w, w+4} -> K rows; {w+8, w+12} -> V rows
    #pragma unroll
    for (int ni = 0; ni < 4; ni++) {
        int n = w + 4 * ni;
        const float* wr = (ni < 2) ? (wk + (size_t)(n * 16 + lm) * 128)
                                   : (wv + (size_t)((n - 8) * 16 + lm) * 128);
        #pragma unroll
        for (int kc = 0; kc < 4; kc++)
            BKV[ni][kc] = cvt8(*(const float4*)(wr + kc * 32 + quad * 8),
                               *(const float4*)(wr + kc * 32 + quad * 8 + 4));
    }
    __syncthreads();

    // ---- P2: K,V = x * w^T over 144 halo positions. Wave owns 4 N-tiles,
    // loops all 9 M-tiles. K -> sK[pos][o] row-major; V -> sVT[o][pos].
    for (int m = 0; m < 9; m++) {
        f16x8 A[4];
        #pragma unroll
        for (int kc = 0; kc < 4; kc++)
            A[kc] = *(const f16x8*)(sX + (m * 16 + lm) * SXW + kc * 32 + quad * 8);
        #pragma unroll
        for (int ni = 0; ni < 4; ni++) {
            f32x4 acc = {0.f, 0.f, 0.f, 0.f};
            #pragma unroll
            for (int kc = 0; kc < 4; kc++)
                acc = __builtin_amdgcn_mfma_f32_16x16x32_f16(A[kc], BKV[ni][kc], acc, 0, 0, 0);
            int n = w + 4 * ni;
            if (ni < 2) {
                #pragma unroll
                for (int r = 0; r < 4; r++)
                    sK[(m * 16 + quad * 4 + r) * SXW + n * 16 + lm] = (_Float16)acc[r];
            } else {
                f16x4 tv;
                #pragma unroll
                for (int r = 0; r < 4; r++) tv[r] = (_Float16)acc[r];
                *(f16x4*)(sVT + ((n - 8) * 16 + lm) * SVW + m * 16 + quad * 4) = tv;
            }
        }
    }

    // ---- P3: Q GEMM for the 64 tile pixels (wave w -> M-tile w)
    {
        int qpx = w * 16 + lm;
        int hrow = ((qpx >> 3) + 2) * 12 + (qpx & 7) + 2;
        f16x8 A[4];
        #pragma unroll
        for (int kc = 0; kc < 4; kc++)
            A[kc] = *(const f16x8*)(sX + hrow * SXW + kc * 32 + quad * 8);
        for (int n = 0; n < 8; n++) {
            const float* wr = wq + (size_t)(n * 16 + lm) * 128;
            f32x4 acc = {0.f, 0.f, 0.f, 0.f};
            #pragma unroll
            for (int kc = 0; kc < 4; kc++) {
                f16x8 Bf = cvt8(*(const float4*)(wr + kc * 32 + quad * 8),
                                *(const float4*)(wr + kc * 32 + quad * 8 + 4));
                acc = __builtin_amdgcn_mfma_f32_16x16x32_f16(A[kc], Bf, acc, 0, 0, 0);
            }
            #pragma unroll
            for (int r = 0; r < 4; r++)
                sQ[(w * 16 + quad * 4 + r) * SXW + n * 16 + lm] = (_Float16)acc[r];
        }
    }
    __syncthreads();

    const int px = lane;                 // softmax pixel owned per-lane
    const int ly = px >> 3, lx = px & 7;

    for (int h = 0; h < 4; h++) {
        // ---- QK^T dense: S[px][pos], N-tiles(pos) split {w, w+4, w+8}
        {
            f16x8 A[4];
            #pragma unroll
            for (int m = 0; m < 4; m++)
                A[m] = *(const f16x8*)(sQ + (m * 16 + lm) * SXW + h * 32 + quad * 8);
            #pragma unroll
            for (int ni = 0; ni < 3; ni++) {
                int n = w + 4 * ni;
                if (n < 9) {
                    f16x8 B = *(const f16x8*)(sK + (n * 16 + lm) * SXW + h * 32 + quad * 8);
                    #pragma unroll
                    for (int m = 0; m < 4; m++) {
                        f32x4 acc = {0.f, 0.f, 0.f, 0.f};
                        acc = __builtin_amdgcn_mfma_f32_16x16x32_f16(A[m], B, acc, 0, 0, 0);
                        #pragma unroll
                        for (int r = 0; r < 4; r++)
                            sS[(m * 16 + quad * 4 + r) * SSW + n * 16 + lm] = acc[r];
                    }
                }
            }
        }
        __syncthreads();

        // ---- softmax over the 25 window positions (all 4 waves duplicate)
        float ev[25]; float inv;
        {
            const float scale = 0.17677669529663689f;
            float sv[25];
            #pragma unroll
            for (int p = 0; p < 25; p++) {
                int hp = (ly + p / 5) * 12 + lx + p % 5;
                sv[p] = sS[px * SSW + hp] * scale;
            }
            float mx = sv[0];
            #pragma unroll
            for (int p = 1; p < 25; p++) mx = fmaxf(mx, sv[p]);
            float sum = 0.f;
            #pragma unroll
            for (int p = 0; p < 25; p++) { ev[p] = __expf(sv[p] - mx); sum += ev[p]; }
            inv = 1.f / sum;
            if (w == 0) sInv[px] = inv;
        }
        __syncthreads();   // all S reads complete before P overwrites region A

        // ---- write P: zero own column segment, scatter f16(e) values
        {
            _Float16* pr = sP + px * SVW;
            const int s0 = w * 40, s1 = (w == 3) ? SVW : (w * 40 + 40);
            f16x4 z4 = {(_Float16)0, (_Float16)0, (_Float16)0, (_Float16)0};
            for (int cb = s0; cb < s1; cb += 4)
                *(f16x4*)(pr + cb) = z4;
            #pragma unroll
            for (int p = 0; p < 25; p++) {
                int hp = (ly + p / 5) * 12 + lx + p % 5;
                if (hp >= s0 && hp < s1) pr[hp] = (_Float16)ev[p];
            }
        }
        __syncthreads();

        // ---- PV: out[px][d] = (sum_pos P*V) * inv ; wave w -> M-tile w
        {
            f16x8 A[5];
            #pragma unroll
            for (int k5 = 0; k5 < 5; k5++)
                A[k5] = *(const f16x8*)(sP + (w * 16 + lm) * SVW + k5 * 32 + quad * 8);
            float ivr[4];
            *(float4*)ivr = *(const float4*)(sInv + w * 16 + quad * 4);
            #pragma unroll
            for (int n = 0; n < 2; n++) {
                f32x4 acc = {0.f, 0.f, 0.f, 0.f};
                #pragma unroll
                for (int k5 = 0; k5 < 5; k5++) {
                    f16x8 B = *(const f16x8*)(sVT + (h * 32 + n * 16 + lm) * SVW + k5 * 32 + quad * 8);
                    acc = __builtin_amdgcn_mfma_f32_16x16x32_f16(A[k5], B, acc, 0, 0, 0);
                }
                #pragma unroll
                for (int r = 0; r < 4; r++)
                    sAo[(w * 16 + quad * 4 + r) * SXW + h * 32 + n * 16 + lm] =
                        (_Float16)(acc[r] * ivr[r]);
            }
        }
        __syncthreads();   // protects P/S region reuse by next head's QK
    }

    // ---- P5: proj. out[c][px] = sum_o wp[c][o] * ao[px][o]
    {
        f16x8 Aw[2][4];
        #pragma unroll
        for (int mi = 0; mi < 2; mi++) {
            const float* wr = wp + (size_t)((w * 2 + mi) * 16 + lm) * 128;
            #pragma unroll
            for (int kc = 0; kc < 4; kc++)
                Aw[mi][kc] = cvt8(*(const float4*)(wr + kc * 32 + quad * 8),
                                  *(const float4*)(wr + kc * 32 + quad * 8 + 4));
        }
        #pragma unroll
        for (int n = 0; n < 4; n++) {
            f16x8 Bf[4];
            #pragma unroll
            for (int kc = 0; kc < 4; kc++)
                Bf[kc] = *(const f16x8*)(sAo + (n * 16 + lm) * SXW + kc * 32 + quad * 8);
            int pxc = n * 16 + lm;
            int gp = (y0 + (pxc >> 3)) * 96 + x0 + (pxc & 7);
            #pragma unroll
            for (int mi = 0; mi < 2; mi++) {
                f32x4 acc = {0.f, 0.f, 0.f, 0.f};
                #pragma unroll
                for (int kc = 0; kc < 4; kc++)
                    acc = __builtin_amdgcn_mfma_f32_16x16x32_f16(Aw[mi][kc], Bf[kc], acc, 0, 0, 0);
                int c0 = (w * 2 + mi) * 16 + quad * 4;
                #pragma unroll
                for (int r = 0; r < 4; r++)
                    ob[(size_t)(c0 + r) * PP + gp] = acc[r];
            }
        }
    }
}

extern "C" void kernel_launch(void* const* d_in, const int* in_sizes, int n_in,
                              void* d_out, int out_size, void* d_ws, size_t ws_size,
                              hipStream_t stream)
{
    const float* x  = (const float*)d_in[0];
    const float* wq = (const float*)d_in[1];
    const float* wk = (const float*)d_in[2];
    const float* wv = (const float*)d_in[3];
    const float* wp = (const float*)d_in[4];
    float* out = (float*)d_out;

    fused_attn<<<dim3(12, 12, 2), 256, 0, stream>>>(x, wq, wk, wv, wp, out);
}

// Round 3
// 123.352 us; speedup vs baseline: 1.3246x; 1.3246x over previous
//
#include <hip/hip_runtime.h>
#include <hip/hip_fp16.h>

#define PP 9216   // 96*96 pixels per batch

typedef _Float16 f16x8 __attribute__((ext_vector_type(8)));
typedef _Float16 f16x4 __attribute__((ext_vector_type(4)));
typedef float    f32x4 __attribute__((ext_vector_type(4)));

// LDS strides (elements)
#define SXW 136   // sX / sK / sQ / sAo row stride (halfs), 272B rows
#define SVW 72    // sVT / sP row stride (halfs), 144B rows
#define SSW 68    // sS row stride (dwords) -> 2-way max on scatter

// byte offsets
#define OFF_X   0        // sX 64*136*2 = 17408 ; overlaid by sS 4*16*68*4 = 17408
#define OFF_K   17408    // sK 64*136*2 = 17408
#define OFF_VT  34816    // sVT 128*72*2 = 18432
#define OFF_Q   53248    // sQ 16*136*2 = 4352
#define OFF_P   57600    // sP 4*16*72*2 = 9216
#define OFF_AO  66816    // sAo 16*136*2 = 4352
#define OFF_INV 71168    // 4*16*4 = 256
#define LDS_BYTES 71424  // <= 80KB -> 2 blocks/CU

__device__ __forceinline__ f16x8 cvt8(float4 u0, float4 u1) {
    f16x8 r;
    r[0] = (_Float16)u0.x; r[1] = (_Float16)u0.y;
    r[2] = (_Float16)u0.z; r[3] = (_Float16)u0.w;
    r[4] = (_Float16)u1.x; r[5] = (_Float16)u1.y;
    r[6] = (_Float16)u1.z; r[7] = (_Float16)u1.w;
    return r;
}

// ---------------------------------------------------------------------------
// Fully fused window self-attention, 4x4 px tile per block (8x8 halo = 64 pos).
// 256 threads = 4 waves. 3 barriers total; per-head attention is wave-local
// (wave w owns head w: QK^T -> softmax -> PV with no cross-wave sync).
// grid (24,24,2) = 1152 blocks, 71.4KB LDS -> 2 blocks/CU.
// ---------------------------------------------------------------------------
__global__ __launch_bounds__(256, 2) void fused_attn(
    const float* __restrict__ x,  const float* __restrict__ wq,
    const float* __restrict__ wk, const float* __restrict__ wv,
    const float* __restrict__ wp, float* __restrict__ out)
{
    __shared__ __align__(16) char smem[LDS_BYTES];
    _Float16* sX  = (_Float16*)(smem + OFF_X);
    float*    sS  = (float*)   (smem + OFF_X);   // overlays sX (dead after P3)
    _Float16* sK  = (_Float16*)(smem + OFF_K);
    _Float16* sVT = (_Float16*)(smem + OFF_VT);
    _Float16* sQ  = (_Float16*)(smem + OFF_Q);
    _Float16* sP  = (_Float16*)(smem + OFF_P);
    _Float16* sAo = (_Float16*)(smem + OFF_AO);
    float*    sInv= (float*)   (smem + OFF_INV);

    const int t = threadIdx.x;
    const int w = t >> 6, lane = t & 63, lm = lane & 15, quad = lane >> 4;
    const int x0 = blockIdx.x * 4, y0 = blockIdx.y * 4, b = blockIdx.z;
    const float* xb = x + (size_t)b * 128 * PP;
    float* ob = out + (size_t)b * 128 * PP;

    // ---- P1: stage 8x8 halo x 128ch, f32 -> f16 transposed into sX[pos][c].
    // Half-wave per channel: 32 lanes x float2 cover the 64 halo positions.
    #pragma unroll
    for (int i = 0; i < 16; i++) {
        int c   = i * 8 + (t >> 5);
        int pos = (t & 31) * 2;
        int gy = y0 - 2 + (pos >> 3);
        int gx = x0 - 2 + (pos & 7);          // even; pairs never straddle edge
        float2 v = make_float2(0.f, 0.f);
        if ((unsigned)gy < 96u && (unsigned)gx < 96u)
            v = *(const float2*)(xb + (size_t)c * PP + gy * 96 + gx);
        sX[pos * SXW + c]       = (_Float16)v.x;
        sX[(pos + 1) * SXW + c] = (_Float16)v.y;
    }

    // hoist K/V and Q weight fragments (global, no LDS dep) over the barrier
    f16x8 BKV[4][4];   // ni 0,1 -> K N-tiles {w,w+4}; ni 2,3 -> V tiles {w,w+4}
    #pragma unroll
    for (int ni = 0; ni < 4; ni++) {
        int n = w + 4 * ni;
        const float* wr = (ni < 2) ? (wk + (size_t)(n * 16 + lm) * 128)
                                   : (wv + (size_t)((n - 8) * 16 + lm) * 128);
        #pragma unroll
        for (int kc = 0; kc < 4; kc++)
            BKV[ni][kc] = cvt8(*(const float4*)(wr + kc * 32 + quad * 8),
                               *(const float4*)(wr + kc * 32 + quad * 8 + 4));
    }
    f16x8 BQ[2][4];    // wave w -> Q N-tiles {2w, 2w+1}
    #pragma unroll
    for (int nn = 0; nn < 2; nn++) {
        const float* wr = wq + (size_t)((w * 2 + nn) * 16 + lm) * 128;
        #pragma unroll
        for (int kc = 0; kc < 4; kc++)
            BQ[nn][kc] = cvt8(*(const float4*)(wr + kc * 32 + quad * 8),
                              *(const float4*)(wr + kc * 32 + quad * 8 + 4));
    }
    __syncthreads();

    // ---- P2: K,V = X * W^T for all 64 halo positions (OOB rows are 0 -> K,V=0,
    // which reproduces the reference's zero-padded windows exactly).
    #pragma unroll
    for (int m = 0; m < 4; m++) {
        f16x8 A[4];
        #pragma unroll
        for (int kc = 0; kc < 4; kc++)
            A[kc] = *(const f16x8*)(sX + (m * 16 + lm) * SXW + kc * 32 + quad * 8);
        #pragma unroll
        for (int ni = 0; ni < 4; ni++) {
            f32x4 acc = {0.f, 0.f, 0.f, 0.f};
            #pragma unroll
            for (int kc = 0; kc < 4; kc++)
                acc = __builtin_amdgcn_mfma_f32_16x16x32_f16(A[kc], BKV[ni][kc], acc, 0, 0, 0);
            int n = w + 4 * ni;
            if (ni < 2) {
                #pragma unroll
                for (int r = 0; r < 4; r++)
                    sK[(m * 16 + quad * 4 + r) * SXW + n * 16 + lm] = (_Float16)acc[r];
            } else {
                f16x4 tv;
                #pragma unroll
                for (int r = 0; r < 4; r++) tv[r] = (_Float16)acc[r];
                *(f16x4*)(sVT + ((n - 8) * 16 + lm) * SVW + m * 16 + quad * 4) = tv;
            }
        }
    }

    // ---- P3: Q for the 16 tile pixels (1 M-tile; wave w -> out-ch tiles 2w,2w+1)
    {
        int hrow = ((lm >> 2) + 2) * 8 + (lm & 3) + 2;
        f16x8 A[4];
        #pragma unroll
        for (int kc = 0; kc < 4; kc++)
            A[kc] = *(const f16x8*)(sX + hrow * SXW + kc * 32 + quad * 8);
        #pragma unroll
        for (int nn = 0; nn < 2; nn++) {
            f32x4 acc = {0.f, 0.f, 0.f, 0.f};
            #pragma unroll
            for (int kc = 0; kc < 4; kc++)
                acc = __builtin_amdgcn_mfma_f32_16x16x32_f16(A[kc], BQ[nn][kc], acc, 0, 0, 0);
            int n = w * 2 + nn;
            #pragma unroll
            for (int r = 0; r < 4; r++)
                sQ[(quad * 4 + r) * SXW + n * 16 + lm] = (_Float16)acc[r];
        }
    }
    __syncthreads();   // sK/sVT/sQ ready; sX dead (sS may overwrite)

    // ---- per-head attention, wave-local: h == w
    {
        const int h = w;
        float*    sSh = sS + h * 16 * SSW;
        _Float16* sPh = sP + h * 16 * SVW;

        // QK^T: S[px][pos] = Q[px][:32] . K[pos][:32]  (single K-chunk, K=32)
        f16x8 Aq = *(const f16x8*)(sQ + lm * SXW + h * 32 + quad * 8);
        #pragma unroll
        for (int n = 0; n < 4; n++) {
            f16x8 Bk = *(const f16x8*)(sK + (n * 16 + lm) * SXW + h * 32 + quad * 8);
            f32x4 acc = {0.f, 0.f, 0.f, 0.f};
            acc = __builtin_amdgcn_mfma_f32_16x16x32_f16(Aq, Bk, acc, 0, 0, 0);
            #pragma unroll
            for (int r = 0; r < 4; r++)
                sSh[(quad * 4 + r) * SSW + n * 16 + lm] = acc[r];
        }

        // softmax: 4 lanes per pixel, each owns 16 of the 64 halo positions;
        // out-of-window -> -1e30 -> exp == 0 (implicit P zero-fill).
        const int spx = lane >> 2, sub = lane & 3;
        const int py = spx >> 2, pxx = spx & 3;
        float sv[16];
        #pragma unroll
        for (int j4 = 0; j4 < 4; j4++)
            *(float4*)(sv + j4 * 4) = *(const float4*)(sSh + spx * SSW + sub * 16 + j4 * 4);
        const float scale = 0.17677669529663689f;
        float sj[16];
        float mx = -1e30f;
        #pragma unroll
        for (int j = 0; j < 16; j++) {
            int pos = sub * 16 + j;
            int hy = pos >> 3, hx = pos & 7;
            bool memb = (hy >= py) & (hy < py + 5) & (hx >= pxx) & (hx < pxx + 5);
            sj[j] = memb ? sv[j] * scale : -1e30f;
            mx = fmaxf(mx, sj[j]);
        }
        mx = fmaxf(mx, __shfl_xor(mx, 1));
        mx = fmaxf(mx, __shfl_xor(mx, 2));
        float sum = 0.f;
        f16x8 ev[2];
        #pragma unroll
        for (int j = 0; j < 16; j++) {
            float e = __expf(sj[j] - mx);
            sum += e;
            ev[j >> 3][j & 7] = (_Float16)e;
        }
        sum += __shfl_xor(sum, 1);
        sum += __shfl_xor(sum, 2);
        *(f16x8*)(sPh + spx * SVW + sub * 16)     = ev[0];
        *(f16x8*)(sPh + spx * SVW + sub * 16 + 8) = ev[1];
        if (sub == 0) sInv[h * 16 + spx] = 1.f / sum;

        // PV: out[px][d] = (sum_pos P*V) * inv   (K = 64 = 2 chunks)
        f16x8 Ap[2];
        #pragma unroll
        for (int kk = 0; kk < 2; kk++)
            Ap[kk] = *(const f16x8*)(sPh + lm * SVW + kk * 32 + quad * 8);
        float ivr[4];
        *(float4*)ivr = *(const float4*)(sInv + h * 16 + quad * 4);
        #pragma unroll
        for (int n = 0; n < 2; n++) {
            f32x4 acc = {0.f, 0.f, 0.f, 0.f};
            #pragma unroll
            for (int kk = 0; kk < 2; kk++) {
                f16x8 Bv = *(const f16x8*)(sVT + (h * 32 + n * 16 + lm) * SVW + kk * 32 + quad * 8);
                acc = __builtin_amdgcn_mfma_f32_16x16x32_f16(Ap[kk], Bv, acc, 0, 0, 0);
            }
            #pragma unroll
            for (int r = 0; r < 4; r++)
                sAo[(quad * 4 + r) * SXW + h * 32 + n * 16 + lm] =
                    (_Float16)(acc[r] * ivr[r]);
        }
    }
    __syncthreads();   // sAo ready (all heads)

    // ---- P5: proj. out[c][px] = sum_o wp[c][o] * ao[px][o]; wave w -> c-tiles 2w,2w+1
    {
        f16x8 Aw[2][4];
        #pragma unroll
        for (int mi = 0; mi < 2; mi++) {
            const float* wr = wp + (size_t)((w * 2 + mi) * 16 + lm) * 128;
            #pragma unroll
            for (int kc = 0; kc < 4; kc++)
                Aw[mi][kc] = cvt8(*(const float4*)(wr + kc * 32 + quad * 8),
                                  *(const float4*)(wr + kc * 32 + quad * 8 + 4));
        }
        f16x8 Bf[4];
        #pragma unroll
        for (int kc = 0; kc < 4; kc++)
            Bf[kc] = *(const f16x8*)(sAo + lm * SXW + kc * 32 + quad * 8);
        int gp = (y0 + (lm >> 2)) * 96 + x0 + (lm & 3);
        #pragma unroll
        for (int mi = 0; mi < 2; mi++) {
            f32x4 acc = {0.f, 0.f, 0.f, 0.f};
            #pragma unroll
            for (int kc = 0; kc < 4; kc++)
                acc = __builtin_amdgcn_mfma_f32_16x16x32_f16(Aw[mi][kc], Bf[kc], acc, 0, 0, 0);
            int c0 = (w * 2 + mi) * 16 + quad * 4;
            #pragma unroll
            for (int r = 0; r < 4; r++)
                ob[(size_t)(c0 + r) * PP + gp] = acc[r];
        }
    }
}

extern "C" void kernel_launch(void* const* d_in, const int* in_sizes, int n_in,
                              void* d_out, int out_size, void* d_ws, size_t ws_size,
                              hipStream_t stream)
{
    const float* x  = (const float*)d_in[0];
    const float* wq = (const float*)d_in[1];
    const float* wk = (const float*)d_in[2];
    const float* wv = (const float*)d_in[3];
    const float* wp = (const float*)d_in[4];
    float* out = (float*)d_out;

    fused_attn<<<dim3(24, 24, 2), 256, 0, stream>>>(x, wq, wk, wv, wp, out);
}

// Round 4
// 107.862 us; speedup vs baseline: 1.5148x; 1.1436x over previous
//
#include <hip/hip_runtime.h>
#include <hip/hip_fp16.h>

#define PP 9216   // 96*96 pixels per batch

typedef _Float16 f16x8 __attribute__((ext_vector_type(8)));
typedef _Float16 f16x4 __attribute__((ext_vector_type(4)));
typedef _Float16 h2    __attribute__((ext_vector_type(2)));
typedef float    f32x4 __attribute__((ext_vector_type(4)));

// LDS strides (elements)
#define SXW 136   // sX / sK / sQ / sAo row stride (halfs), 272B rows
#define SSW 68    // sS row stride (dwords)
#define SPW 72    // sP row stride (halfs) inside the S slab
#define SVW 72    // sVT row stride (halfs)

// byte offsets (lifetime overlays):
//  R0: sX (P1..P3) -> sS 4 head-slabs of 4352B (QKT..softmax) -> sP inside slab
//  R1: sK (P2..QKT) -> sVT 4 wave-slabs of 4608B (post-B3..PV)
//  R2: sQ (P3..QKT) -> sAo (PV..proj)
#define OFF_X    0        // 17408
#define OFF_K    17408    // 18432
#define OFF_Q    35840    // 4352
#define OFF_INV  40192    // 256
#define LDS_BYTES 40448   // 4 blocks/CU (4*40448 <= 160KiB)

// ---------------------------------------------------------------------------
// prep_w: one-time f32 -> f16 weight conversion.
// wqkv16[o][c], o in [0,384): 0-127 wq, 128-255 wk, 256-383 wv. wp16[c][o].
// ---------------------------------------------------------------------------
__global__ __launch_bounds__(256) void prep_w(
    const float* __restrict__ wq, const float* __restrict__ wk,
    const float* __restrict__ wv, const float* __restrict__ wp,
    _Float16* __restrict__ wqkv16, _Float16* __restrict__ wp16)
{
    int e = (blockIdx.x * 256 + threadIdx.x) * 4;   // 4 elems/thread, 65536 total
    const float* src;
    _Float16* dst;
    if (e < 49152) {
        int o = e >> 7;
        src = (o < 128) ? (wq + (size_t)o * 128)
            : (o < 256) ? (wk + (size_t)(o - 128) * 128)
                        : (wv + (size_t)(o - 256) * 128);
        src += (e & 127);
        dst = wqkv16 + e;
    } else {
        int j = e - 49152;
        src = wp + j;
        dst = wp16 + j;
    }
    float4 v = *(const float4*)src;
    f16x4 h;
    h[0] = (_Float16)v.x; h[1] = (_Float16)v.y;
    h[2] = (_Float16)v.z; h[3] = (_Float16)v.w;
    *(f16x4*)dst = h;
}

// ---------------------------------------------------------------------------
// Fully fused window self-attention, 4x4 px tile (8x8 halo), 4 waves,
// wave w owns head w. 4 barriers. 40.4KB LDS -> 4 blocks/CU.
// ---------------------------------------------------------------------------
__global__ __launch_bounds__(256, 4) void fused_attn(
    const float* __restrict__ x, const _Float16* __restrict__ wqkv,
    const _Float16* __restrict__ wp16, float* __restrict__ out)
{
    __shared__ __align__(16) char smem[LDS_BYTES];
    _Float16* sX  = (_Float16*)(smem + OFF_X);
    _Float16* sK  = (_Float16*)(smem + OFF_K);
    _Float16* sQ  = (_Float16*)(smem + OFF_Q);
    _Float16* sAo = (_Float16*)(smem + OFF_Q);    // overlays sQ (post-B3)
    float*    sInv= (float*)(smem + OFF_INV);

    const int t = threadIdx.x;
    const int w = t >> 6, lane = t & 63, lm = lane & 15, quad = lane >> 4;

    // XCD-bijective swizzle: 1152 blocks = 8 XCDs x 144-block contiguous chunks
    const int wgid = (blockIdx.x & 7) * 144 + (blockIdx.x >> 3);
    const int b = wgid / 576;
    const int rem = wgid - b * 576;
    const int x0 = (rem % 24) * 4, y0 = (rem / 24) * 4;

    const float* xb = x + (size_t)b * 128 * PP;
    float* ob = out + (size_t)b * 128 * PP;

    // ---- P1: stage 8x8 halo x 128ch, f32 -> f16 transposed into sX[pos][c]
    #pragma unroll
    for (int i = 0; i < 16; i++) {
        int c   = i * 8 + (t >> 5);
        int pos = (t & 31) * 2;
        int gy = y0 - 2 + (pos >> 3);
        int gx = x0 - 2 + (pos & 7);          // even; pairs never straddle edge
        float2 v = make_float2(0.f, 0.f);
        if ((unsigned)gy < 96u && (unsigned)gx < 96u)
            v = *(const float2*)(xb + (size_t)c * PP + gy * 96 + gx);
        sX[pos * SXW + c]       = (_Float16)v.x;
        sX[(pos + 1) * SXW + c] = (_Float16)v.y;
    }
    __syncthreads();   // B1: sX ready

    // ---- P2: K,V GEMM. K N-tiles {w, w+4} -> sK; V N-tiles {2w,2w+1} (head w's
    // V channels) -> packed registers (staged to LDS only after B3).
    h2 vpk[2][4][2];
    #pragma unroll
    for (int m = 0; m < 4; m++) {
        f16x8 A[4];
        #pragma unroll
        for (int kc = 0; kc < 4; kc++)
            A[kc] = *(const f16x8*)(sX + (m * 16 + lm) * SXW + kc * 32 + quad * 8);
        #pragma unroll
        for (int ni = 0; ni < 2; ni++) {
            int n = w + 4 * ni;
            const _Float16* wr = wqkv + (size_t)(128 + n * 16 + lm) * 128;
            f32x4 acc = {0.f, 0.f, 0.f, 0.f};
            #pragma unroll
            for (int kc = 0; kc < 4; kc++)
                acc = __builtin_amdgcn_mfma_f32_16x16x32_f16(
                    A[kc], *(const f16x8*)(wr + kc * 32 + quad * 8), acc, 0, 0, 0);
            #pragma unroll
            for (int r = 0; r < 4; r++)
                sK[(m * 16 + quad * 4 + r) * SXW + n * 16 + lm] = (_Float16)acc[r];
        }
        #pragma unroll
        for (int nn = 0; nn < 2; nn++) {
            const _Float16* wr = wqkv + (size_t)(256 + (2 * w + nn) * 16 + lm) * 128;
            f32x4 acc = {0.f, 0.f, 0.f, 0.f};
            #pragma unroll
            for (int kc = 0; kc < 4; kc++)
                acc = __builtin_amdgcn_mfma_f32_16x16x32_f16(
                    A[kc], *(const f16x8*)(wr + kc * 32 + quad * 8), acc, 0, 0, 0);
            vpk[nn][m][0][0] = (_Float16)acc[0]; vpk[nn][m][0][1] = (_Float16)acc[1];
            vpk[nn][m][1][0] = (_Float16)acc[2]; vpk[nn][m][1][1] = (_Float16)acc[3];
        }
    }

    // ---- P3: Q for the 16 tile pixels; wave w -> out-ch tiles {2w, 2w+1}
    {
        int hrow = ((lm >> 2) + 2) * 8 + (lm & 3) + 2;
        f16x8 A[4];
        #pragma unroll
        for (int kc = 0; kc < 4; kc++)
            A[kc] = *(const f16x8*)(sX + hrow * SXW + kc * 32 + quad * 8);
        #pragma unroll
        for (int nn = 0; nn < 2; nn++) {
            const _Float16* wr = wqkv + (size_t)((2 * w + nn) * 16 + lm) * 128;
            f32x4 acc = {0.f, 0.f, 0.f, 0.f};
            #pragma unroll
            for (int kc = 0; kc < 4; kc++)
                acc = __builtin_amdgcn_mfma_f32_16x16x32_f16(
                    A[kc], *(const f16x8*)(wr + kc * 32 + quad * 8), acc, 0, 0, 0);
            #pragma unroll
            for (int r = 0; r < 4; r++)
                sQ[(quad * 4 + r) * SXW + (2 * w + nn) * 16 + lm] = (_Float16)acc[r];
        }
    }
    __syncthreads();   // B2: sK/sQ ready; sX dead (sS overlays)

    // ---- head w, wave-local. S/P slab for head w overlays sX region.
    float*    sSh = (float*)(smem + OFF_X + w * 4352);
    _Float16* sPh = (_Float16*)(smem + OFF_X + w * 4352);

    // QK^T: S[px][pos], single K-chunk (d = 32)
    {
        f16x8 Aq = *(const f16x8*)(sQ + lm * SXW + w * 32 + quad * 8);
        #pragma unroll
        for (int n = 0; n < 4; n++) {
            f16x8 Bk = *(const f16x8*)(sK + (n * 16 + lm) * SXW + w * 32 + quad * 8);
            f32x4 acc = {0.f, 0.f, 0.f, 0.f};
            acc = __builtin_amdgcn_mfma_f32_16x16x32_f16(Aq, Bk, acc, 0, 0, 0);
            #pragma unroll
            for (int r = 0; r < 4; r++)
                sSh[(quad * 4 + r) * SSW + n * 16 + lm] = acc[r];
        }
    }

    // softmax: 4 lanes per pixel; out-of-window -> -1e30 -> exp == 0.
    // P (f16) overwrites the S slab (same-wave in-order LDS: reads precede writes).
    {
        const int spx = lane >> 2, sub = lane & 3;
        const int py = spx >> 2, pxx = spx & 3;
        float sv[16];
        #pragma unroll
        for (int j4 = 0; j4 < 4; j4++)
            *(float4*)(sv + j4 * 4) = *(const float4*)(sSh + spx * SSW + sub * 16 + j4 * 4);
        const float scale = 0.17677669529663689f;
        float sj[16];
        float mx = -1e30f;
        #pragma unroll
        for (int j = 0; j < 16; j++) {
            int pos = sub * 16 + j;
            int hy = pos >> 3, hx = pos & 7;
            bool memb = (hy >= py) & (hy < py + 5) & (hx >= pxx) & (hx < pxx + 5);
            sj[j] = memb ? sv[j] * scale : -1e30f;
            mx = fmaxf(mx, sj[j]);
        }
        mx = fmaxf(mx, __shfl_xor(mx, 1));
        mx = fmaxf(mx, __shfl_xor(mx, 2));
        float sum = 0.f;
        f16x8 ev0, ev1;
        #pragma unroll
        for (int j = 0; j < 16; j++) {
            float e = __expf(sj[j] - mx);
            sum += e;
            if (j < 8) ev0[j] = (_Float16)e; else ev1[j - 8] = (_Float16)e;
        }
        sum += __shfl_xor(sum, 1);
        sum += __shfl_xor(sum, 2);
        *(f16x8*)(sPh + spx * SPW + sub * 16)     = ev0;
        *(f16x8*)(sPh + spx * SPW + sub * 16 + 8) = ev1;
        if (sub == 0) sInv[w * 16 + spx] = 1.f / sum;
    }
    __syncthreads();   // B3: all sK/sQ reads done -> sVT/sAo overlays legal

    // ---- stage held V registers into per-wave sVT slab (over dead sK)
    _Float16* sVh = (_Float16*)(smem + OFF_K + w * 4608);
    #pragma unroll
    for (int nn = 0; nn < 2; nn++)
        #pragma unroll
        for (int m = 0; m < 4; m++)
            #pragma unroll
            for (int rp = 0; rp < 2; rp++)
                *(h2*)(sVh + (nn * 16 + lm) * SVW + m * 16 + quad * 4 + rp * 2)
                    = vpk[nn][m][rp];

    // ---- PV: out[px][d] = (sum_pos P*V) * inv  (K = 64 = 2 chunks)
    {
        f16x8 Ap[2];
        #pragma unroll
        for (int kc = 0; kc < 2; kc++)
            Ap[kc] = *(const f16x8*)(sPh + lm * SPW + kc * 32 + quad * 8);
        float ivr[4];
        *(float4*)ivr = *(const float4*)(sInv + w * 16 + quad * 4);
        #pragma unroll
        for (int nd = 0; nd < 2; nd++) {
            f32x4 acc = {0.f, 0.f, 0.f, 0.f};
            #pragma unroll
            for (int kc = 0; kc < 2; kc++) {
                f16x8 Bv = *(const f16x8*)(sVh + (nd * 16 + lm) * SVW + kc * 32 + quad * 8);
                acc = __builtin_amdgcn_mfma_f32_16x16x32_f16(Ap[kc], Bv, acc, 0, 0, 0);
            }
            #pragma unroll
            for (int r = 0; r < 4; r++)
                sAo[(quad * 4 + r) * SXW + w * 32 + nd * 16 + lm] =
                    (_Float16)(acc[r] * ivr[r]);
        }
    }
    __syncthreads();   // B4: sAo ready (all heads)

    // ---- proj: out[c][px] = sum_o wp[c][o] * ao[px][o]; wave w -> c-tiles {2w,2w+1}
    {
        f16x8 Bf[4];
        #pragma unroll
        for (int kc = 0; kc < 4; kc++)
            Bf[kc] = *(const f16x8*)(sAo + lm * SXW + kc * 32 + quad * 8);
        int gp = (y0 + (lm >> 2)) * 96 + x0 + (lm & 3);
        #pragma unroll
        for (int mi = 0; mi < 2; mi++) {
            const _Float16* wr = wp16 + (size_t)((w * 2 + mi) * 16 + lm) * 128;
            f32x4 acc = {0.f, 0.f, 0.f, 0.f};
            #pragma unroll
            for (int kc = 0; kc < 4; kc++)
                acc = __builtin_amdgcn_mfma_f32_16x16x32_f16(
                    *(const f16x8*)(wr + kc * 32 + quad * 8), Bf[kc], acc, 0, 0, 0);
            int c0 = (w * 2 + mi) * 16 + quad * 4;
            #pragma unroll
            for (int r = 0; r < 4; r++)
                ob[(size_t)(c0 + r) * PP + gp] = acc[r];
        }
    }
}

extern "C" void kernel_launch(void* const* d_in, const int* in_sizes, int n_in,
                              void* d_out, int out_size, void* d_ws, size_t ws_size,
                              hipStream_t stream)
{
    const float* x  = (const float*)d_in[0];
    const float* wq = (const float*)d_in[1];
    const float* wk = (const float*)d_in[2];
    const float* wv = (const float*)d_in[3];
    const float* wp = (const float*)d_in[4];
    float* out = (float*)d_out;

    _Float16* wqkv16 = (_Float16*)d_ws;          // 384*128
    _Float16* wp16   = wqkv16 + 49152;           // 128*128

    prep_w<<<dim3(64), 256, 0, stream>>>(wq, wk, wv, wp, wqkv16, wp16);
    fused_attn<<<dim3(1152), 256, 0, stream>>>(x, wqkv16, wp16, out);
}